// Round 4
// baseline (750.584 us; speedup 1.0000x reference)
//
#include <hip/hip_runtime.h>

// NLinearMemoryEfficient: out[b,n,o] = sum_i x[b,n,i]*W[n,o,i] + bias[n,o]
// B=8192, N=256, D_IN=64, D_OUT=128, fp32 in/out. bf16 MFMA (thr 7.09e-2).
//
// Barrier-free pipeline:
//  - block = 256 thr (4 waves), one n, S=8 tiles of TB=64 rows. grid=4096.
//  - Wave w owns rows [w*16, w*16+16) of each tile -> x frags have NO
//    cross-wave reuse -> stage x in WAVE-PRIVATE LDS (2 KB/wave, single
//    buffer; same-wave DS ops execute in order -> no barrier needed).
//  - Only ONE __syncthreads in the whole kernel (after W/bias staging).
//    Waves drift freely -> vmcnt stalls de-correlate across waves.
//  - Depth-2 register prefetch: tile j+2 global loads issued at top of
//    tile j's body, packed to LDS at bottom of tile j+1 (~2 bodies > HBM
//    latency). Coalesced float4 loads (4 rows x 16 chunks = 4x256B/instr).
//  - LDS 25 KB, __launch_bounds__(256,4) -> 4 blocks/CU = 16 waves/CU.
//  - MFMA roles: A=W (rows=o), B=x (cols=b): lane stores ONE float4 of 4
//    consecutive o per (ot); wave covers all 128 o -> 512B/row across burst.
//  - C/D layout (verified r2/r3): col=lane&15 (=b), row=(lane>>4)*4+reg (=o).

typedef short  short8  __attribute__((ext_vector_type(8)));
typedef float  float4v __attribute__((ext_vector_type(4)));

constexpr int NFEAT = 256;
constexpr int DI    = 64;
constexpr int DO    = 128;
constexpr int TB    = 64;    // rows per tile
constexpr int S     = 8;     // tiles per block

__device__ __forceinline__ uint32_t pack_bf16(float a, float b) {
    uint32_t ua = __builtin_bit_cast(uint32_t, a);
    uint32_t ub = __builtin_bit_cast(uint32_t, b);
    ua += 0x7fffu + ((ua >> 16) & 1u);   // RNE
    ub += 0x7fffu + ((ub >> 16) & 1u);
    return (ua >> 16) | (ub & 0xffff0000u);
}

__global__ __launch_bounds__(256, 4) void nlinear_mfma_bfree_kernel(
    const float* __restrict__ x, const float* __restrict__ W,
    const float* __restrict__ bias, float* __restrict__ out)
{
    // frag layout: [tile16][ks][lane][slot] u32; element k = ks*32+khi*8+w*2+e
    __shared__ __align__(16) uint32_t wfrag[8][2][64][4];   // 16 KB, shared
    __shared__ __align__(16) uint32_t xpriv[4][2][64][4];   //  8 KB, per-wave
    __shared__ float bias_l[DO];                            // 512 B

    // XCD-bijective swizzle: 4096 blocks -> 512 consecutive per XCD
    // (32 n values -> 1 MB W working set per XCD L2).
    const int bid  = blockIdx.x;
    const int swz  = (bid & 7) * 512 + (bid >> 3);
    const int n    = swz >> 4;         // 0..255
    const int slab = swz & 15;         // 16 slabs of S*TB = 512 rows
    const uint32_t b_blk = (uint32_t)slab * (TB * S);

    const int t   = threadIdx.x;
    const int l   = t & 63;
    const int wv  = t >> 6;
    const int llo = l & 15;
    const int lhi = l >> 4;

    const float4* Xg4 = (const float4*)x;
    // wave-private rows: wv*16 + p*4 + lhi; chunk = llo (fully coalesced)
    const uint32_t rbase = b_blk + wv * 16 + lhi;

    float4 xrA[4], xrB[4];

#define LOADX(JT, DST)                                              \
    _Pragma("unroll")                                               \
    for (int p = 0; p < 4; ++p) {                                   \
        uint32_t b = rbase + (uint32_t)(JT) * TB + p * 4;           \
        DST[p] = Xg4[(b * NFEAT + n) * 16u + llo];                  \
    }

    LOADX(0, xrA);
    LOADX(1, xrB);

    // ---- stage W_n as bf16 A-fragments (rows = o), cooperative ----
    const float4* Wn4 = (const float4*)(W + (size_t)n * DO * DI);
#pragma unroll
    for (int p = 0; p < 8; ++p) {
        int idx  = p * 256 + t;              // o = idx>>4 (= p*16 + t>>4)
        float4 f = Wn4[idx];
        int lane = (((idx >> 1) & 3) << 4) | (t >> 4);
        int ks   = (idx >> 3) & 1;
        int sp   = (idx & 1) * 2;
        uint2 pk = make_uint2(pack_bf16(f.x, f.y), pack_bf16(f.z, f.w));
        *(uint2*)&wfrag[p][ks][lane][sp] = pk;
    }
    if (t < DO) bias_l[t] = bias[n * DO + t];
    __syncthreads();   // the only block-wide barrier

    // pack: thread's 4 float4 (rows p*4+lhi, i0 = llo*4) -> xpriv[wv]
    const int pk_ks  = (llo >> 3) & 1;
    const int pk_khi = (llo >> 1) & 3;
    const int pk_sp  = (llo & 1) * 2;

#define PACKX(SRC)                                                  \
    _Pragma("unroll")                                               \
    for (int p = 0; p < 4; ++p) {                                   \
        int fl = (pk_khi << 4) | (p * 4 + lhi);                     \
        uint2 pk = make_uint2(pack_bf16(SRC[p].x, SRC[p].y),        \
                              pack_bf16(SRC[p].z, SRC[p].w));       \
        *(uint2*)&xpriv[wv][pk_ks][fl][pk_sp] = pk;                 \
    }

    PACKX(xrA);   // tile 0 -> LDS

    for (int j = 0; j < S; ++j) {
        float4* xr_next = (j & 1) ? xrA : xrB;   // holds tile j+1
        float4* xr_free = (j & 1) ? xrB : xrA;   // tile j packed -> reuse

        if (j + 2 < S) { LOADX(j + 2, xr_free); }

        // B-operand x frags for tile j (wave-private, conflict-free b128)
        short8 xf0 = ((const short8*)&xpriv[wv][0][0][0])[l];
        short8 xf1 = ((const short8*)&xpriv[wv][1][0][0])[l];

        float4v acc[8];
#pragma unroll
        for (int ot = 0; ot < 8; ++ot) {
            acc[ot] = *(const float4v*)&bias_l[ot * 16 + lhi * 4];  // broadcast
            short8 wf0 = ((const short8*)&wfrag[ot][0][0][0])[l];
            short8 wf1 = ((const short8*)&wfrag[ot][1][0][0])[l];
            acc[ot] = __builtin_amdgcn_mfma_f32_16x16x32_bf16(wf0, xf0, acc[ot], 0, 0, 0);
            acc[ot] = __builtin_amdgcn_mfma_f32_16x16x32_bf16(wf1, xf1, acc[ot], 0, 0, 0);
        }

        // store: row b = b_blk+j*64+wv*16+llo, o = ot*16 + lhi*4 + reg
        uint32_t ob = ((b_blk + (uint32_t)j * TB + wv * 16 + llo) * NFEAT + n) * DO + lhi * 4;
#pragma unroll
        for (int ot = 0; ot < 8; ++ot)
            *(float4v*)&out[ob + ot * 16u] = acc[ot];

        // pack tile j+1 into the SAME wave-private region: safe, same-wave
        // DS ops execute in order (reads above already issued)
        if (j + 1 < S) { PACKX(xr_next); }
    }
#undef LOADX
#undef PACKX
}

extern "C" void kernel_launch(void* const* d_in, const int* in_sizes, int n_in,
                              void* d_out, int out_size, void* d_ws, size_t ws_size,
                              hipStream_t stream) {
    const float* xp = (const float*)d_in[0];
    const float* Wp = (const float*)d_in[1];
    const float* bp = (const float*)d_in[2];
    float* op = (float*)d_out;

    dim3 grid(4096);   // 256 n * 16 slabs
    dim3 block(256);
    hipLaunchKernelGGL(nlinear_mfma_bfree_kernel, grid, block, 0, stream, xp, Wp, bp, op);
}

// Round 5
// 346.794 us; speedup vs baseline: 2.1644x; 2.1644x over previous
//
#include <hip/hip_runtime.h>

// NLinearMemoryEfficient: out[b,n,o] = sum_i x[b,n,i]*W[n,o,i] + bias[n,o]
// B=8192, N=256, D_IN=64, D_OUT=128, fp32 in/out. bf16 MFMA (thr 7.09e-2).
//
// r5 = r3's proven compute + FULL-LINE STORE epilogue.
// Key finding (r4 counters): stores that deliver <128B per row per
// instruction trigger L2 partial-line RMW -> ~1.6x write amplification +
// out-line refetch (~1 GB junk HBM traffic). r1's 128B-contiguous-per-row
// stores measured zero amplification. Fix: transpose acc through a tiny
// wave-private LDS patch so each store instr writes 4 rows x 256B (2 full
// 128B lines per row).
//
//  - block = 256 thr (4 waves, wr x wc = 2x2), one n, S=8 tiles of 128 rows.
//  - W_n packed once into LDS A-frag layout (16 KB); bias as MFMA C operand.
//  - x: coalesced global float4 loads (reg prefetch 1 tile ahead), packed
//    to bf16 frags in single-buffered LDS (16 KB), 2 barriers/tile.
//  - Epilogue: per bt, acc -> patch[16][68] (uniform banks) -> row-major
//    read -> float4 stores, 256B/row contiguous, 128B-line aligned.
//  - LDS 49.9 KB -> 3 blocks/CU (12 waves). C/D layout verified r2-r4.

typedef short  short8  __attribute__((ext_vector_type(8)));
typedef float  float4v __attribute__((ext_vector_type(4)));

constexpr int NFEAT  = 256;
constexpr int DI     = 64;
constexpr int DO     = 128;
constexpr int TILE_B = 128;
constexpr int S      = 8;     // tiles per block

__device__ __forceinline__ uint32_t pack_bf16(float a, float b) {
    uint32_t ua = __builtin_bit_cast(uint32_t, a);
    uint32_t ub = __builtin_bit_cast(uint32_t, b);
    ua += 0x7fffu + ((ua >> 16) & 1u);   // RNE
    ub += 0x7fffu + ((ub >> 16) & 1u);
    return (ua >> 16) | (ub & 0xffff0000u);
}

__global__ __launch_bounds__(256, 3) void nlinear_mfma_fs_kernel(
    const float* __restrict__ x, const float* __restrict__ W,
    const float* __restrict__ bias, float* __restrict__ out)
{
    // frag layout: [tile16][ks][lane][slot] u32; k = ks*32 + lhi*8 + j
    __shared__ __align__(16) uint32_t wfrag[8][2][64][4];   // 16 KB (o-tiles)
    __shared__ __align__(16) uint32_t xfrag[8][2][64][4];   // 16 KB (b-tiles)
    __shared__ __align__(16) float    patch[4][16][68];     // 17408 B, per-wave

    // XCD-bijective swizzle: 2048 blocks -> 256/XCD -> 32 n per XCD L2.
    const int bid  = blockIdx.x;
    const int swz  = (bid & 7) * 256 + (bid >> 3);
    const int n    = swz >> 3;         // 0..255
    const int slab = swz & 7;          // 8 slabs of S*128 = 1024 rows
    const uint32_t b_base = (uint32_t)slab * (TILE_B * S);

    const int t   = threadIdx.x;
    const int l   = t & 63;
    const int wv  = t >> 6;
    const int wr  = wv >> 1;           // b-half (0..1)
    const int wc  = wv & 1;            // o-half (0..1)
    const int llo = l & 15;
    const int lhi = l >> 4;

    // ---- stage W_n as bf16 A-fragments (rows = o) ----
    const float4* Wn4 = (const float4*)(W + (size_t)n * DO * DI);
#pragma unroll
    for (int p = 0; p < 8; ++p) {
        int idx  = p * 256 + t;              // o = idx>>4, i0 = (idx&15)*4
        float4 f = Wn4[idx];
        int lane = (((idx >> 1) & 3) << 4) | (t >> 4);
        int ks   = (idx >> 3) & 1;
        int sp   = (idx & 1) * 2;
        uint2 pk = make_uint2(pack_bf16(f.x, f.y), pack_bf16(f.z, f.w));
        *(uint2*)&wfrag[p][ks][lane][sp] = pk;
    }

    // bias: 4 consecutive o per lane -> C operand of ks=0 MFMA
    float4v bias4[4];
#pragma unroll
    for (int ot = 0; ot < 4; ++ot)
        bias4[ot] = *(const float4v*)&bias[n * DO + wc * 64 + ot * 16 + lhi * 4];

    const float4* Xg4 = (const float4*)x;
    float4 xr[8];

#define LOADX(JT)                                                   \
    _Pragma("unroll")                                               \
    for (int p = 0; p < 8; ++p) {                                   \
        int idx = p * 256 + t;                                      \
        uint32_t b = b_base + (uint32_t)(JT) * TILE_B + (idx >> 4); \
        xr[p] = Xg4[b * 4096u + n * 16u + (idx & 15)];              \
    }

    LOADX(0);

    for (int j = 0; j < S; ++j) {
        __syncthreads();               // xfrag free (prev tile's reads done)

        // pack tile j regs -> frags
#pragma unroll
        for (int p = 0; p < 8; ++p) {
            int idx  = p * 256 + t;
            int lane = (((idx >> 1) & 3) << 4) | (t >> 4);
            int ks   = (idx >> 3) & 1;
            int sp   = (idx & 1) * 2;
            uint2 pk = make_uint2(pack_bf16(xr[p].x, xr[p].y),
                                  pack_bf16(xr[p].z, xr[p].w));
            *(uint2*)&xfrag[p][ks][lane][sp] = pk;
        }
        if (j + 1 < S) { LOADX(j + 1); }   // full tile of latency ahead

        __syncthreads();               // xfrag ready

        // ---- compute: D(o,b) = W_n * x^T + bias ----
        float4v acc[4][4];
#pragma unroll
        for (int ks = 0; ks < 2; ++ks) {
            short8 wf[4];
#pragma unroll
            for (int ot = 0; ot < 4; ++ot)
                wf[ot] = *(const short8*)&wfrag[wc * 4 + ot][ks][l][0];
#pragma unroll
            for (int bt = 0; bt < 4; ++bt) {
                short8 xf = *(const short8*)&xfrag[wr * 4 + bt][ks][l][0];
#pragma unroll
                for (int ot = 0; ot < 4; ++ot) {
                    acc[bt][ot] = __builtin_amdgcn_mfma_f32_16x16x32_bf16(
                        wf[ot], xf, (ks == 0) ? bias4[ot] : acc[bt][ot], 0, 0, 0);
                }
            }
        }

        // ---- full-line store epilogue (wave-private patch, in-order DS) --
        // acc[bt][ot][reg]: row b = ..bt*16+llo, o = wc*64 + ot*16 + lhi*4+reg
#pragma unroll
        for (int bt = 0; bt < 4; ++bt) {
#pragma unroll
            for (int ot = 0; ot < 4; ++ot)
                *(float4v*)&patch[wv][llo][ot * 16 + lhi * 4] = acc[bt][ot];
            // read row-major: 16 lanes cover one row's 256B (2 full lines)
#pragma unroll
            for (int m = 0; m < 4; ++m) {
                float4v v = *(const float4v*)&patch[wv][m * 4 + lhi][llo * 4];
                uint32_t b = b_base + (uint32_t)j * TILE_B + wr * 64
                           + bt * 16 + m * 4 + lhi;
                *(float4v*)&out[b * 32768u + n * 128u + wc * 64u + llo * 4u] = v;
            }
        }
    }
#undef LOADX
}

extern "C" void kernel_launch(void* const* d_in, const int* in_sizes, int n_in,
                              void* d_out, int out_size, void* d_ws, size_t ws_size,
                              hipStream_t stream) {
    const float* xp = (const float*)d_in[0];
    const float* Wp = (const float*)d_in[1];
    const float* bp = (const float*)d_in[2];
    float* op = (float*)d_out;

    dim3 grid(2048);   // 256 n * 8 slabs
    dim3 block(256);
    hipLaunchKernelGGL(nlinear_mfma_fs_kernel, grid, block, 0, stream, xp, Wp, bp, op);
}